// Round 2
// baseline (411.827 us; speedup 1.0000x reference)
//
#include <hip/hip_runtime.h>

#define CH   288
#define GRPS 32
#define CPG  9
#define IMH  64
#define IMW  64
#define HW   4096
#define NB   8
#define BN_EPS 1e-5f

typedef short bf16x8 __attribute__((ext_vector_type(8)));
typedef float f32x4  __attribute__((ext_vector_type(4)));

// ws layout (bytes)
#define XT_OFF   0u            // x_t / tmp_t bf16 [b][p][c]  (18,874,368 B)
#define WIB_OFF  18874368u     // Wi bf16 [288][288]          (165,888 B)
#define WOS_OFF  19040256u     // Wo*scale bf16 [288][288]    (165,888 B)
#define S1_OFF   19206144u     // per-channel sum   f32 [288]
#define S2_OFF   19207296u     // per-channel sumsq f32 [288]
#define SC_OFF   19208448u     // scale f32 [288]
#define SH_OFF   19209600u     // shift f32 [288]
#define BO2_OFF  19210752u     // folded bias f32 [288]

__device__ __forceinline__ unsigned short f2b(float f) {
    unsigned int u = __float_as_uint(f);
    return (unsigned short)((u + 0x7fffu + ((u >> 16) & 1u)) >> 16);
}
__device__ __forceinline__ float b2f(unsigned short h) {
    return __uint_as_float(((unsigned int)h) << 16);
}

// ---------------------------------------------------------------------------
// K0: x [b][c][p] f32  ->  x_t [b][p][c] bf16 (coalesced both sides via LDS)
// ---------------------------------------------------------------------------
#define TS 40   // LDS px-row stride in bf16 (80 B, 16B-aligned)
__global__ __launch_bounds__(256) void k_transpose(const float* __restrict__ x,
                                                   unsigned short* __restrict__ xt) {
    __shared__ unsigned short T[64 * TS];
    const int tid = threadIdx.x;
    const int p0 = blockIdx.x * 64;
    const int c0 = blockIdx.y * 32;
    const int b  = blockIdx.z;
    #pragma unroll
    for (int it = 0; it < 2; ++it) {
        const int item  = it * 256 + tid;       // 512 items
        const int c_loc = item >> 4;            // 0..31
        const int p4    = item & 15;            // 0..15
        const float4 v = *(const float4*)(x + (size_t)(b * CH + c0 + c_loc) * HW + p0 + p4 * 4);
        const int px = p4 * 4;
        T[(px + 0) * TS + c_loc] = f2b(v.x);
        T[(px + 1) * TS + c_loc] = f2b(v.y);
        T[(px + 2) * TS + c_loc] = f2b(v.z);
        T[(px + 3) * TS + c_loc] = f2b(v.w);
    }
    __syncthreads();
    const int px_loc = tid >> 2;                // 0..63
    const int cq     = tid & 3;                 // 0..3
    const uint4 o = *(const uint4*)((const char*)T + px_loc * (TS * 2) + cq * 16);
    *(uint4*)(xt + ((size_t)b * HW + p0 + px_loc) * CH + c0 + cq * 8) = o;
}

// ---------------------------------------------------------------------------
// K0b: Wi f32 -> bf16
// ---------------------------------------------------------------------------
__global__ __launch_bounds__(256) void k_cvt_wi(const float* __restrict__ Wi,
                                                unsigned short* __restrict__ Wib) {
    const int idx = blockIdx.x * 256 + threadIdx.x;   // 0..20735
    const float4 v = ((const float4*)Wi)[idx];
    unsigned short h[4] = {f2b(v.x), f2b(v.y), f2b(v.z), f2b(v.w)};
    *(uint2*)(Wib + (size_t)idx * 4) = *(const uint2*)h;
}

// ---------------------------------------------------------------------------
// K1: MFMA GEMM1 + fused BN-stats.
//   tmp_t[px][c] = relu( dot(x_t[px][:], Wi[c][:]) + bi[c] )  (bf16, in-place)
// Block: 32 px x 288 c, 4 waves. Wave: 16 px x 144 c (9 MFMA tiles).
// A-frag = Wi rows, B-frag = x_t rows, all direct global (L1/L2-served).
// ---------------------------------------------------------------------------
__global__ __launch_bounds__(256) void k_gemm1(const unsigned short* __restrict__ Wib,
                                               const float* __restrict__ bi,
                                               unsigned short* __restrict__ xt,   // in & out
                                               float* __restrict__ s1g,
                                               float* __restrict__ s2g) {
    const int tid  = threadIdx.x;
    const int wave = tid >> 6;
    const int lane = tid & 63;
    const int q    = lane >> 4;
    const int r    = lane & 15;
    const int p0   = blockIdx.x * 32;
    const int b    = blockIdx.y;
    const int pxb  = p0 + (wave & 1) * 16;        // wave's 16-px base
    const int ct0  = (wave >> 1) * 9;             // wave's c-tile base

    const unsigned short* brow = xt + ((size_t)b * HW + pxb + r) * CH;
    const unsigned short* abase = Wib + (size_t)(ct0 * 16 + r) * CH;

    f32x4 acc[9];
    #pragma unroll
    for (int i = 0; i < 9; ++i) acc[i] = (f32x4)0.0f;

    for (int k0 = 0; k0 < CH; k0 += 32) {
        const bf16x8 bfr = *(const bf16x8*)(brow + k0 + q * 8);
        #pragma unroll
        for (int ct = 0; ct < 9; ++ct) {
            const bf16x8 afr = *(const bf16x8*)(abase + (size_t)ct * 16 * CH + k0 + q * 8);
            acc[ct] = __builtin_amdgcn_mfma_f32_16x16x32_bf16(afr, bfr, acc[ct], 0, 0, 0);
        }
    }

    __syncthreads();   // all waves done READING x_t rows before in-place store

    const int px = pxb + r;
    #pragma unroll
    for (int ct = 0; ct < 9; ++ct) {
        const int cbase = (ct0 + ct) * 16 + q * 4;
        float v[4];
        #pragma unroll
        for (int i = 0; i < 4; ++i) {
            float t = acc[ct][i] + bi[cbase + i];
            v[i] = fmaxf(t, 0.0f);
        }
        unsigned short h[4] = {f2b(v[0]), f2b(v[1]), f2b(v[2]), f2b(v[3])};
        *(uint2*)(xt + ((size_t)b * HW + px) * CH + cbase) = *(const uint2*)h;
        // stats: reduce over r (lanes sharing q-group), then one atomic per c
        float a1[4], a2[4];
        #pragma unroll
        for (int i = 0; i < 4; ++i) { a1[i] = v[i]; a2[i] = v[i] * v[i]; }
        #pragma unroll
        for (int m = 1; m < 16; m <<= 1) {
            #pragma unroll
            for (int i = 0; i < 4; ++i) {
                a1[i] += __shfl_xor(a1[i], m, 64);
                a2[i] += __shfl_xor(a2[i], m, 64);
            }
        }
        if (r == 0) {
            #pragma unroll
            for (int i = 0; i < 4; ++i) {
                atomicAdd(&s1g[cbase + i], a1[i]);
                atomicAdd(&s2g[cbase + i], a2[i]);
            }
        }
    }
}

// ---------------------------------------------------------------------------
// K2a: BN scale/shift
// ---------------------------------------------------------------------------
__global__ __launch_bounds__(320) void k_scale(const float* __restrict__ s1,
                                               const float* __restrict__ s2,
                                               const float* __restrict__ gamma,
                                               const float* __restrict__ beta,
                                               float* __restrict__ scale,
                                               float* __restrict__ shift) {
    const int c = threadIdx.x;
    if (c < CH) {
        const float inv = 1.0f / (float)(NB * HW);
        const float mean = s1[c] * inv;
        const float var  = s2[c] * inv - mean * mean;
        const float rs   = rsqrtf(var + BN_EPS);
        const float sc   = gamma[c] * rs;
        scale[c] = sc;
        shift[c] = beta[c] - mean * sc;
    }
}

// ---------------------------------------------------------------------------
// K2b: Wo_s[m][k] = bf16(Wo[m][k]*scale[k]); bo2[m] = bo[m] + sum_k Wo[m][k]*shift[k]
// ---------------------------------------------------------------------------
__global__ __launch_bounds__(64) void k_fold(const float* __restrict__ Wo,
                                             const float* __restrict__ bo,
                                             const float* __restrict__ scale,
                                             const float* __restrict__ shift,
                                             unsigned short* __restrict__ Wos,
                                             float* __restrict__ bo2) {
    const int m = blockIdx.x;
    const int t = threadIdx.x;
    float s = 0.0f;
    for (int k = t; k < CH; k += 64) {
        const float wv = Wo[(size_t)m * CH + k];
        s += wv * shift[k];
        Wos[(size_t)m * CH + k] = f2b(wv * scale[k]);
    }
    #pragma unroll
    for (int off = 32; off > 0; off >>= 1) s += __shfl_down(s, off, 64);
    if (t == 0) bo2[m] = bo[m] + s;
}

// ---------------------------------------------------------------------------
// K3: MFMA GEMM2 (ker = Wo_s @ tmp + bo2) -> kerL in LDS -> fused involution.
// Block: 32 px (half image row) x 288 ker-ch. Wave split as K1.
// ---------------------------------------------------------------------------
#define KLS 36   // kerL px stride (bf16): 72 B rows, 8B-aligned reads
__global__ __launch_bounds__(256) void k_gemm2_invol(const unsigned short* __restrict__ tmp_t,
                                                     const unsigned short* __restrict__ Wos,
                                                     const float* __restrict__ bo2,
                                                     const float* __restrict__ x,
                                                     float* __restrict__ out) {
    __shared__ unsigned short kerL[CH * KLS];   // 20736 B

    const int tid  = threadIdx.x;
    const int wave = tid >> 6;
    const int lane = tid & 63;
    const int q    = lane >> 4;
    const int r    = lane & 15;
    const int p0   = blockIdx.x * 32;
    const int b    = blockIdx.y;
    const int h    = p0 >> 6;        // image row
    const int w0   = p0 & 63;        // 0 or 32
    const int pxb  = (wave & 1) * 16;      // local px base
    const int mt0  = (wave >> 1) * 9;

    const unsigned short* brow = tmp_t + ((size_t)b * HW + p0 + pxb + r) * CH;
    const unsigned short* abase = Wos + (size_t)(mt0 * 16 + r) * CH;

    f32x4 acc[9];
    #pragma unroll
    for (int i = 0; i < 9; ++i) acc[i] = (f32x4)0.0f;

    for (int k0 = 0; k0 < CH; k0 += 32) {
        const bf16x8 bfr = *(const bf16x8*)(brow + k0 + q * 8);
        #pragma unroll
        for (int mt = 0; mt < 9; ++mt) {
            const bf16x8 afr = *(const bf16x8*)(abase + (size_t)mt * 16 * CH + k0 + q * 8);
            acc[mt] = __builtin_amdgcn_mfma_f32_16x16x32_bf16(afr, bfr, acc[mt], 0, 0, 0);
        }
    }

    // stage ker (+bias) into LDS: kerL[c][px_loc]
    const int px_loc = pxb + r;
    #pragma unroll
    for (int mt = 0; mt < 9; ++mt) {
        const int cbase = (mt0 + mt) * 16 + q * 4;
        #pragma unroll
        for (int i = 0; i < 4; ++i)
            kerL[(cbase + i) * KLS + px_loc] = f2b(acc[mt][i] + bo2[cbase + i]);
    }
    __syncthreads();

    // involution: thread (tm, tn) handles ch = tm+32i, px quad tn (4 px)
    const int tm = tid >> 3;    // 0..31
    const int tn = tid & 7;     // 0..7
    const int wb = w0 + tn * 4; // global w of quad start
    #pragma unroll 1
    for (int i = 0; i < 9; ++i) {
        const int ch = tm + 32 * i;
        const int cb = (ch / CPG) * CPG;
        // load x neighborhood rows into regs: 3 rows x 6 cols
        float xv[3][6];
        #pragma unroll
        for (int dr = 0; dr < 3; ++dr) {
            const int hh = h + dr - 1;
            const bool rv = (hh >= 0) && (hh < IMH);
            const float* xr = x + ((size_t)(b * CH + ch) * IMH + (rv ? hh : 0)) * IMW;
            if (rv) {
                const float4 m4 = *(const float4*)(xr + wb);
                xv[dr][1] = m4.x; xv[dr][2] = m4.y; xv[dr][3] = m4.z; xv[dr][4] = m4.w;
                xv[dr][0] = (wb > 0)       ? xr[wb - 1] : 0.0f;
                xv[dr][5] = (wb + 4 < IMW) ? xr[wb + 4] : 0.0f;
            } else {
                #pragma unroll
                for (int j = 0; j < 6; ++j) xv[dr][j] = 0.0f;
            }
        }
        float o[4] = {0.0f, 0.0f, 0.0f, 0.0f};
        #pragma unroll
        for (int k = 0; k < 9; ++k) {
            const int dr = k / 3, dc = k % 3;
            const uint2 kk = *(const uint2*)(kerL + (cb + k) * KLS + tn * 4);
            const unsigned short* ks = (const unsigned short*)&kk;
            #pragma unroll
            for (int j = 0; j < 4; ++j)
                o[j] += b2f(ks[j]) * xv[dr][j + dc];
        }
        float4 ov = {o[0], o[1], o[2], o[3]};
        *(float4*)(out + ((size_t)(b * CH + ch) * IMH + h) * IMW + wb) = ov;
    }
}

// ---------------------------------------------------------------------------
extern "C" void kernel_launch(void* const* d_in, const int* in_sizes, int n_in,
                              void* d_out, int out_size, void* d_ws, size_t ws_size,
                              hipStream_t stream) {
    const float* x     = (const float*)d_in[0];
    const float* Wi    = (const float*)d_in[1];
    const float* bi    = (const float*)d_in[2];
    const float* gamma = (const float*)d_in[3];
    const float* beta  = (const float*)d_in[4];
    const float* Wo    = (const float*)d_in[5];
    const float* bo    = (const float*)d_in[6];
    float* out = (float*)d_out;

    char* ws = (char*)d_ws;
    unsigned short* xt  = (unsigned short*)(ws + XT_OFF);
    unsigned short* Wib = (unsigned short*)(ws + WIB_OFF);
    unsigned short* Wos = (unsigned short*)(ws + WOS_OFF);
    float* s1    = (float*)(ws + S1_OFF);
    float* s2    = (float*)(ws + S2_OFF);
    float* scale = (float*)(ws + SC_OFF);
    float* shift = (float*)(ws + SH_OFF);
    float* bo2   = (float*)(ws + BO2_OFF);

    k_transpose<<<dim3(HW / 64, CH / 32, NB), 256, 0, stream>>>(x, xt);
    k_cvt_wi<<<dim3(CH * CH / 1024), 256, 0, stream>>>(Wi, Wib);
    hipMemsetAsync(ws + S1_OFF, 0, 2 * CH * sizeof(float), stream);
    k_gemm1<<<dim3(HW / 32, NB), 256, 0, stream>>>(Wib, bi, xt, s1, s2);
    k_scale<<<dim3(1), 320, 0, stream>>>(s1, s2, gamma, beta, scale, shift);
    k_fold<<<dim3(CH), 64, 0, stream>>>(Wo, bo, scale, shift, Wos, bo2);
    k_gemm2_invol<<<dim3(HW / 32, NB), 256, 0, stream>>>(xt, Wos, bo2, x, out);
}

// Round 3
// 337.502 us; speedup vs baseline: 1.2202x; 1.2202x over previous
//
#include <hip/hip_runtime.h>

#define CH   288
#define GRPS 32
#define CPG  9
#define IMH  64
#define IMW  64
#define HW   4096
#define NB   8
#define NPX  (NB * HW)     // 32768 total pixel rows
#define BN_EPS 1e-5f

typedef short bf16x8 __attribute__((ext_vector_type(8)));
typedef float f32x4  __attribute__((ext_vector_type(4)));

// ws layout (bytes)
#define XT_OFF   0u            // x_t / tmp_t bf16 [b][p][c]  (18,874,368 B)
#define WIB_OFF  18874368u     // Wi bf16 [288][288]
#define WOS_OFF  19040256u     // Wo*scale bf16 [288][288]
#define S1_OFF   19206144u     // per-channel sum   f32 [288]
#define S2_OFF   19207296u     // per-channel sumsq f32 [288]
#define SC_OFF   19208448u     // scale f32 [288]
#define SH_OFF   19209600u     // shift f32 [288]
#define BO2_OFF  19210752u     // folded bias f32 [288]

__device__ __forceinline__ unsigned short f2b(float f) {
    unsigned int u = __float_as_uint(f);
    return (unsigned short)((u + 0x7fffu + ((u >> 16) & 1u)) >> 16);
}
__device__ __forceinline__ float b2f(unsigned short h) {
    return __uint_as_float(((unsigned int)h) << 16);
}

// async global->LDS, 16B per lane; dst = wave-uniform base + lane*16
#define GLDS(g, l) __builtin_amdgcn_global_load_lds( \
    (const __attribute__((address_space(1))) void*)(g), \
    (__attribute__((address_space(3))) void*)(l), 16, 0, 0)

__device__ __forceinline__ f32x4 mfma16(bf16x8 a, bf16x8 b, f32x4 c) {
    return __builtin_amdgcn_mfma_f32_16x16x32_bf16(a, b, c, 0, 0, 0);
}

// ---------------------------------------------------------------------------
// K0: x [b][c][p] f32 -> x_t [b][p][c] bf16 (coalesced both sides via LDS)
// ---------------------------------------------------------------------------
#define TS 40
__global__ __launch_bounds__(256) void k_transpose(const float* __restrict__ x,
                                                   unsigned short* __restrict__ xt) {
    __shared__ unsigned short T[64 * TS];
    const int tid = threadIdx.x;
    const int p0 = blockIdx.x * 64;
    const int c0 = blockIdx.y * 32;
    const int b  = blockIdx.z;
    #pragma unroll
    for (int it = 0; it < 2; ++it) {
        const int item  = it * 256 + tid;
        const int c_loc = item >> 4;
        const int p4    = item & 15;
        const float4 v = *(const float4*)(x + (size_t)(b * CH + c0 + c_loc) * HW + p0 + p4 * 4);
        const int px = p4 * 4;
        T[(px + 0) * TS + c_loc] = f2b(v.x);
        T[(px + 1) * TS + c_loc] = f2b(v.y);
        T[(px + 2) * TS + c_loc] = f2b(v.z);
        T[(px + 3) * TS + c_loc] = f2b(v.w);
    }
    __syncthreads();
    const int px_loc = tid >> 2;
    const int cq     = tid & 3;
    const uint4 o = *(const uint4*)((const char*)T + px_loc * (TS * 2) + cq * 16);
    *(uint4*)(xt + ((size_t)b * HW + p0 + px_loc) * CH + c0 + cq * 8) = o;
}

// ---------------------------------------------------------------------------
// K0b: Wi f32 -> bf16
// ---------------------------------------------------------------------------
__global__ __launch_bounds__(256) void k_cvt_wi(const float* __restrict__ Wi,
                                                unsigned short* __restrict__ Wib) {
    const int idx = blockIdx.x * 256 + threadIdx.x;
    const float4 v = ((const float4*)Wi)[idx];
    unsigned short h[4] = {f2b(v.x), f2b(v.y), f2b(v.z), f2b(v.w)};
    *(uint2*)(Wib + (size_t)idx * 4) = *(const uint2*)h;
}

// ---------------------------------------------------------------------------
// K1: LDS-staged MFMA GEMM1 + fused BN stats.
//   tmp_t[px][c] = relu(dot(x_t[px][:], Wi[c][:]) + bi[c])  (bf16, in-place)
// Block: 64 px x 288 c, 4 waves; wave = 32 px x 144 c (2x9 MFMA tiles).
// LDS rows: 0..63 = x-tile rows (64B/row), 64..351 = Wi rows.
// XOR chunk swizzle: slot (row,p) holds source chunk p ^ ((row>>1)&3).
// ---------------------------------------------------------------------------
__global__ __launch_bounds__(256) void k_gemm1(const unsigned short* __restrict__ Wib,
                                               const float* __restrict__ bi,
                                               unsigned short* __restrict__ xt,
                                               float* __restrict__ s1g,
                                               float* __restrict__ s2g) {
    __shared__ unsigned short smem[(64 + 288) * 32];   // 22528 B
    char* smc = (char*)smem;

    const int tid  = threadIdx.x;
    const int wave = tid >> 6;
    const int lane = tid & 63;
    const int q    = lane >> 4;
    const int r    = lane & 15;
    const int pxh  = wave & 1;      // 32-px half
    const int chh  = wave >> 1;     // 144-c half
    const int p0   = blockIdx.x * 64;

    f32x4 acc[2][9];
    #pragma unroll
    for (int t = 0; t < 2; ++t)
        #pragma unroll
        for (int j = 0; j < 9; ++j) acc[t][j] = (f32x4)0.0f;

    const int lrow = lane >> 2;          // staging: row within segment
    const int lp   = lane & 3;           // staging: chunk position

    for (int k0 = 0; k0 < CH; k0 += 32) {
        // ---- stage: 22 segments of 1KB (4 x-tile + 18 Wi-tile) ----
        for (int s = wave; s < 22; s += 4) {
            const int row = s * 16 + lrow;           // LDS row 0..351
            const int sc  = lp ^ ((row >> 1) & 3);   // swizzled source chunk
            const unsigned short* g = (s < 4)
                ? xt  + (size_t)(p0 + row) * CH + k0 + sc * 8
                : Wib + (size_t)(row - 64) * CH + k0 + sc * 8;
            GLDS(g, smc + s * 1024);
        }
        __syncthreads();
        // ---- compute ----
        bf16x8 xf[2];
        #pragma unroll
        for (int t = 0; t < 2; ++t) {
            const int row = pxh * 32 + t * 16 + r;
            xf[t] = *(const bf16x8*)(smc + row * 64 + ((q ^ ((row >> 1) & 3)) * 16));
        }
        #pragma unroll
        for (int j = 0; j < 9; ++j) {
            const int ro = 64 + chh * 144 + j * 16 + r;
            const bf16x8 wf = *(const bf16x8*)(smc + ro * 64 + ((q ^ ((ro >> 1) & 3)) * 16));
            acc[0][j] = mfma16(wf, xf[0], acc[0][j]);
            acc[1][j] = mfma16(wf, xf[1], acc[1][j]);
        }
        __syncthreads();
    }

    // ---- epilogue: bias+relu, bf16 store (in place), fused BN stats ----
    #pragma unroll 1
    for (int j = 0; j < 9; ++j) {
        const int cb = chh * 144 + j * 16 + q * 4;
        const float4 b4 = *(const float4*)(bi + cb);
        float a1[4] = {0.f, 0.f, 0.f, 0.f}, a2[4] = {0.f, 0.f, 0.f, 0.f};
        #pragma unroll
        for (int t = 0; t < 2; ++t) {
            const int px = p0 + pxh * 32 + t * 16 + r;
            unsigned short h[4];
            float v0 = fmaxf(acc[t][j][0] + b4.x, 0.0f);
            float v1 = fmaxf(acc[t][j][1] + b4.y, 0.0f);
            float v2 = fmaxf(acc[t][j][2] + b4.z, 0.0f);
            float v3 = fmaxf(acc[t][j][3] + b4.w, 0.0f);
            h[0] = f2b(v0); h[1] = f2b(v1); h[2] = f2b(v2); h[3] = f2b(v3);
            a1[0] += v0; a1[1] += v1; a1[2] += v2; a1[3] += v3;
            a2[0] += v0 * v0; a2[1] += v1 * v1; a2[2] += v2 * v2; a2[3] += v3 * v3;
            *(uint2*)(xt + (size_t)px * CH + cb) = *(const uint2*)h;
        }
        #pragma unroll
        for (int m = 1; m < 16; m <<= 1) {
            #pragma unroll
            for (int i = 0; i < 4; ++i) {
                a1[i] += __shfl_xor(a1[i], m, 64);
                a2[i] += __shfl_xor(a2[i], m, 64);
            }
        }
        if (r == 0) {
            #pragma unroll
            for (int i = 0; i < 4; ++i) {
                atomicAdd(&s1g[cb + i], a1[i]);
                atomicAdd(&s2g[cb + i], a2[i]);
            }
        }
    }
}

// ---------------------------------------------------------------------------
// K2a: BN scale/shift
// ---------------------------------------------------------------------------
__global__ __launch_bounds__(320) void k_scale(const float* __restrict__ s1,
                                               const float* __restrict__ s2,
                                               const float* __restrict__ gamma,
                                               const float* __restrict__ beta,
                                               float* __restrict__ scale,
                                               float* __restrict__ shift) {
    const int c = threadIdx.x;
    if (c < CH) {
        const float inv = 1.0f / (float)(NB * HW);
        const float mean = s1[c] * inv;
        const float var  = s2[c] * inv - mean * mean;
        const float rs   = rsqrtf(var + BN_EPS);
        const float sc   = gamma[c] * rs;
        scale[c] = sc;
        shift[c] = beta[c] - mean * sc;
    }
}

// ---------------------------------------------------------------------------
// K2b: Wo_s[m][k] = bf16(Wo[m][k]*scale[k]); bo2[m] = bo[m] + Wo[m][:]@shift
// ---------------------------------------------------------------------------
__global__ __launch_bounds__(64) void k_fold(const float* __restrict__ Wo,
                                             const float* __restrict__ bo,
                                             const float* __restrict__ scale,
                                             const float* __restrict__ shift,
                                             unsigned short* __restrict__ Wos,
                                             float* __restrict__ bo2) {
    const int m = blockIdx.x;
    const int t = threadIdx.x;
    float s = 0.0f;
    for (int k = t; k < CH; k += 64) {
        const float wv = Wo[(size_t)m * CH + k];
        s += wv * shift[k];
        Wos[(size_t)m * CH + k] = f2b(wv * scale[k]);
    }
    #pragma unroll
    for (int off = 32; off > 0; off >>= 1) s += __shfl_down(s, off, 64);
    if (t == 0) bo2[m] = bo[m] + s;
}

// ---------------------------------------------------------------------------
// K3: LDS-staged MFMA GEMM2 (ker = Wo_s @ tmp + bo2) -> kerL -> involution.
// Block: 32 px x 288 ker-ch, 4 waves; wave = 16 px x 144 c (9 tiles).
// LDS GEMM rows: 0..287 = Wo_s rows, 288..319 = tmp rows (20480 B);
// kerL bf16 [288][36] (20736 B) aliases the GEMM region after final barrier.
// ---------------------------------------------------------------------------
#define KLS 36
__global__ __launch_bounds__(256) void k_gemm2_invol(const unsigned short* __restrict__ xt,
                                                     const unsigned short* __restrict__ Wos,
                                                     const float* __restrict__ bo2,
                                                     const float* __restrict__ x,
                                                     float* __restrict__ out) {
    __shared__ unsigned short smem[CH * KLS];   // 10368 shorts = 20736 B
    char* smc = (char*)smem;
    unsigned short* kerL = smem;

    const int tid  = threadIdx.x;
    const int wave = tid >> 6;
    const int lane = tid & 63;
    const int q    = lane >> 4;
    const int r    = lane & 15;
    const int pxh  = wave & 1;
    const int chh  = wave >> 1;
    const int p0   = blockIdx.x * 32;
    const int b    = blockIdx.y;
    const int h    = p0 >> 6;
    const int w0   = p0 & 63;
    const size_t rowbase = (size_t)b * HW + p0;

    f32x4 acc[9];
    #pragma unroll
    for (int j = 0; j < 9; ++j) acc[j] = (f32x4)0.0f;

    const int lrow = lane >> 2;
    const int lp   = lane & 3;

    for (int k0 = 0; k0 < CH; k0 += 32) {
        // ---- stage: 20 segments (18 Wo_s + 2 tmp) ----
        for (int s = wave; s < 20; s += 4) {
            const int row = s * 16 + lrow;            // 0..319
            const int sc  = lp ^ ((row >> 1) & 3);
            const unsigned short* g = (s < 18)
                ? Wos + (size_t)row * CH + k0 + sc * 8
                : xt  + (rowbase + row - 288) * CH + k0 + sc * 8;
            GLDS(g, smc + s * 1024);
        }
        __syncthreads();
        // ---- compute ----
        const int xr = 288 + pxh * 16 + r;
        const bf16x8 xf = *(const bf16x8*)(smc + xr * 64 + ((q ^ ((xr >> 1) & 3)) * 16));
        #pragma unroll
        for (int j = 0; j < 9; ++j) {
            const int wr = chh * 144 + j * 16 + r;
            const bf16x8 wf = *(const bf16x8*)(smc + wr * 64 + ((q ^ ((wr >> 1) & 3)) * 16));
            acc[j] = mfma16(wf, xf, acc[j]);
        }
        __syncthreads();   // also guards kerL aliasing after last iteration
    }

    // ---- stage ker (+bias) into LDS: kerL[c][px_loc] ----
    const int pxl = pxh * 16 + r;
    #pragma unroll
    for (int j = 0; j < 9; ++j) {
        const int cb = chh * 144 + j * 16 + q * 4;
        const float4 bz = *(const float4*)(bo2 + cb);
        kerL[(cb + 0) * KLS + pxl] = f2b(acc[j][0] + bz.x);
        kerL[(cb + 1) * KLS + pxl] = f2b(acc[j][1] + bz.y);
        kerL[(cb + 2) * KLS + pxl] = f2b(acc[j][2] + bz.z);
        kerL[(cb + 3) * KLS + pxl] = f2b(acc[j][3] + bz.w);
    }
    __syncthreads();

    // ---- involution: thread (tm,tn) -> ch = tm+32i, px quad tn ----
    const int tm = tid >> 3;
    const int tn = tid & 7;
    const int wb = w0 + tn * 4;
    #pragma unroll 1
    for (int i = 0; i < 9; ++i) {
        const int ch = tm + 32 * i;
        const int cb = (ch / CPG) * CPG;
        float xv[3][6];
        #pragma unroll
        for (int dr = 0; dr < 3; ++dr) {
            const int hh = h + dr - 1;
            const bool rv = (hh >= 0) && (hh < IMH);
            const float* xr2 = x + ((size_t)(b * CH + ch) * IMH + (rv ? hh : 0)) * IMW;
            if (rv) {
                const float4 m4 = *(const float4*)(xr2 + wb);
                xv[dr][1] = m4.x; xv[dr][2] = m4.y; xv[dr][3] = m4.z; xv[dr][4] = m4.w;
                xv[dr][0] = (wb > 0)       ? xr2[wb - 1] : 0.0f;
                xv[dr][5] = (wb + 4 < IMW) ? xr2[wb + 4] : 0.0f;
            } else {
                #pragma unroll
                for (int j = 0; j < 6; ++j) xv[dr][j] = 0.0f;
            }
        }
        float o[4] = {0.0f, 0.0f, 0.0f, 0.0f};
        #pragma unroll
        for (int k = 0; k < 9; ++k) {
            const int dr = k / 3, dc = k % 3;
            const uint2 kk = *(const uint2*)(kerL + (cb + k) * KLS + tn * 4);
            const unsigned short* ks = (const unsigned short*)&kk;
            #pragma unroll
            for (int j = 0; j < 4; ++j)
                o[j] += b2f(ks[j]) * xv[dr][j + dc];
        }
        float4 ov = {o[0], o[1], o[2], o[3]};
        *(float4*)(out + ((size_t)(b * CH + ch) * IMH + h) * IMW + wb) = ov;
    }
}

// ---------------------------------------------------------------------------
extern "C" void kernel_launch(void* const* d_in, const int* in_sizes, int n_in,
                              void* d_out, int out_size, void* d_ws, size_t ws_size,
                              hipStream_t stream) {
    const float* x     = (const float*)d_in[0];
    const float* Wi    = (const float*)d_in[1];
    const float* bi    = (const float*)d_in[2];
    const float* gamma = (const float*)d_in[3];
    const float* beta  = (const float*)d_in[4];
    const float* Wo    = (const float*)d_in[5];
    const float* bo    = (const float*)d_in[6];
    float* out = (float*)d_out;

    char* ws = (char*)d_ws;
    unsigned short* xt  = (unsigned short*)(ws + XT_OFF);
    unsigned short* Wib = (unsigned short*)(ws + WIB_OFF);
    unsigned short* Wos = (unsigned short*)(ws + WOS_OFF);
    float* s1    = (float*)(ws + S1_OFF);
    float* s2    = (float*)(ws + S2_OFF);
    float* scale = (float*)(ws + SC_OFF);
    float* shift = (float*)(ws + SH_OFF);
    float* bo2   = (float*)(ws + BO2_OFF);

    k_transpose<<<dim3(HW / 64, CH / 32, NB), 256, 0, stream>>>(x, xt);
    k_cvt_wi<<<dim3(CH * CH / 1024), 256, 0, stream>>>(Wi, Wib);
    hipMemsetAsync(ws + S1_OFF, 0, 2 * CH * sizeof(float), stream);
    k_gemm1<<<dim3(NPX / 64), 256, 0, stream>>>(Wib, bi, xt, s1, s2);
    k_scale<<<dim3(1), 320, 0, stream>>>(s1, s2, gamma, beta, scale, shift);
    k_fold<<<dim3(CH), 64, 0, stream>>>(Wo, bo, scale, shift, Wos, bo2);
    k_gemm2_invol<<<dim3(HW / 32, NB), 256, 0, stream>>>(xt, Wos, bo2, x, out);
}

// Round 4
// 230.040 us; speedup vs baseline: 1.7902x; 1.4671x over previous
//
#include <hip/hip_runtime.h>

#define CH   288
#define GRPS 32
#define CPG  9
#define IMH  64
#define IMW  64
#define HW   4096
#define NB   8
#define NPX  (NB * HW)     // 32768 total pixel rows
#define BN_EPS 1e-5f

typedef short bf16x8 __attribute__((ext_vector_type(8)));
typedef float f32x4  __attribute__((ext_vector_type(4)));

// ws layout (bytes)
#define XT_OFF   0u            // x_t / tmp_t bf16 [b][p][c]  (18,874,368 B)
#define WIB_OFF  18874368u     // Wi bf16 [288][288]
#define WOS_OFF  19040256u     // Wo*scale bf16 [288][288]
#define S1_OFF   19206144u     // per-channel sum   f32 [288]
#define S2_OFF   19207296u     // per-channel sumsq f32 [288]  (contiguous after s1)
#define SC_OFF   19208448u     // scale f32 [288]
#define SH_OFF   19209600u     // shift f32 [288]
#define BO2_OFF  19210752u     // folded bias f32 [288]

__device__ __forceinline__ unsigned short f2b(float f) {
    unsigned int u = __float_as_uint(f);
    return (unsigned short)((u + 0x7fffu + ((u >> 16) & 1u)) >> 16);
}
__device__ __forceinline__ float b2f(unsigned short h) {
    return __uint_as_float(((unsigned int)h) << 16);
}

// async global->LDS, 16B per lane; dst = wave-uniform base + lane*16
#define GLDS(g, l) __builtin_amdgcn_global_load_lds( \
    (const __attribute__((address_space(1))) void*)(g), \
    (__attribute__((address_space(3))) void*)(l), 16, 0, 0)

__device__ __forceinline__ f32x4 mfma16(bf16x8 a, bf16x8 b, f32x4 c) {
    return __builtin_amdgcn_mfma_f32_16x16x32_bf16(a, b, c, 0, 0, 0);
}

// ---------------------------------------------------------------------------
// K0: x [b][c][p] f32 -> x_t [b][p][c] bf16 (coalesced both sides via LDS)
// ---------------------------------------------------------------------------
#define TS 40
__global__ __launch_bounds__(256) void k_transpose(const float* __restrict__ x,
                                                   unsigned short* __restrict__ xt) {
    __shared__ unsigned short T[64 * TS];
    const int tid = threadIdx.x;
    const int p0 = blockIdx.x * 64;
    const int c0 = blockIdx.y * 32;
    const int b  = blockIdx.z;
    #pragma unroll
    for (int it = 0; it < 2; ++it) {
        const int item  = it * 256 + tid;
        const int c_loc = item >> 4;
        const int p4    = item & 15;
        const float4 v = *(const float4*)(x + (size_t)(b * CH + c0 + c_loc) * HW + p0 + p4 * 4);
        const int px = p4 * 4;
        T[(px + 0) * TS + c_loc] = f2b(v.x);
        T[(px + 1) * TS + c_loc] = f2b(v.y);
        T[(px + 2) * TS + c_loc] = f2b(v.z);
        T[(px + 3) * TS + c_loc] = f2b(v.w);
    }
    __syncthreads();
    const int px_loc = tid >> 2;
    const int cq     = tid & 3;
    const uint4 o = *(const uint4*)((const char*)T + px_loc * (TS * 2) + cq * 16);
    *(uint4*)(xt + ((size_t)b * HW + p0 + px_loc) * CH + c0 + cq * 8) = o;
}

// ---------------------------------------------------------------------------
// K0b: Wi f32 -> bf16
// ---------------------------------------------------------------------------
__global__ __launch_bounds__(256) void k_cvt_wi(const float* __restrict__ Wi,
                                                unsigned short* __restrict__ Wib) {
    const int idx = blockIdx.x * 256 + threadIdx.x;
    const float4 v = ((const float4*)Wi)[idx];
    unsigned short h[4] = {f2b(v.x), f2b(v.y), f2b(v.z), f2b(v.w)};
    *(uint2*)(Wib + (size_t)idx * 4) = *(const uint2*)h;
}

// ---------------------------------------------------------------------------
// K1: LDS-staged MFMA GEMM1 + fused BN stats.
//   tmp_t[px][c] = relu(dot(x_t[px][:], Wi[c][:]) + bi[c])  (bf16, in-place)
// Block: 64 px x 288 c, 4 waves; wave = 32 px x 144 c (2x9 MFMA tiles).
// K-loop LDS rows: 0..63 = x-tile rows, 64..351 = Wi rows (XOR chunk swizzle).
// Epilogue: 2-phase LDS-staged coalesced stores (32 rows x 576 B per phase);
// BN stats via LDS accumulator + one coalesced atomic flush per block.
// ---------------------------------------------------------------------------
__global__ __launch_bounds__(256) void k_gemm1(const unsigned short* __restrict__ Wib,
                                               const float* __restrict__ bi,
                                               unsigned short* __restrict__ xt,
                                               float* __restrict__ s1g) {
    __shared__ unsigned short smem[(64 + 288) * 32];   // 22528 B
    char* smc = (char*)smem;

    const int tid  = threadIdx.x;
    const int wave = tid >> 6;
    const int lane = tid & 63;
    const int q    = lane >> 4;
    const int r    = lane & 15;
    const int pxh  = wave & 1;      // 32-px half
    const int chh  = wave >> 1;     // 144-c half
    const int p0   = blockIdx.x * 64;

    f32x4 acc[2][9];
    #pragma unroll
    for (int t = 0; t < 2; ++t)
        #pragma unroll
        for (int j = 0; j < 9; ++j) acc[t][j] = (f32x4)0.0f;

    const int lrow = lane >> 2;          // staging: row within segment
    const int lp   = lane & 3;           // staging: chunk position

    for (int k0 = 0; k0 < CH; k0 += 32) {
        // ---- stage: 22 segments of 1KB (4 x-tile + 18 Wi-tile) ----
        for (int s = wave; s < 22; s += 4) {
            const int row = s * 16 + lrow;           // LDS row 0..351
            const int sc  = lp ^ ((row >> 1) & 3);   // swizzled source chunk
            const unsigned short* g = (s < 4)
                ? xt  + (size_t)(p0 + row) * CH + k0 + sc * 8
                : Wib + (size_t)(row - 64) * CH + k0 + sc * 8;
            GLDS(g, smc + s * 1024);
        }
        __syncthreads();
        // ---- compute ----
        bf16x8 xf[2];
        #pragma unroll
        for (int t = 0; t < 2; ++t) {
            const int row = pxh * 32 + t * 16 + r;
            xf[t] = *(const bf16x8*)(smc + row * 64 + ((q ^ ((row >> 1) & 3)) * 16));
        }
        #pragma unroll
        for (int j = 0; j < 9; ++j) {
            const int ro = 64 + chh * 144 + j * 16 + r;
            const bf16x8 wf = *(const bf16x8*)(smc + ro * 64 + ((q ^ ((ro >> 1) & 3)) * 16));
            acc[0][j] = mfma16(wf, xf[0], acc[0][j]);
            acc[1][j] = mfma16(wf, xf[1], acc[1][j]);
        }
        __syncthreads();
    }

    // ================= epilogue =================
    // LDS reuse: bytes [0, 18432) = 32-row x 576 B output staging (per phase),
    //            bytes [18432, 20736) = 576-float stats accumulator.
    float* sstat = (float*)(smc + 18432);
    for (int c2 = tid; c2 < 576; c2 += 256) sstat[c2] = 0.0f;
    __syncthreads();

    // ---- BN stats: per-wave shfl reduce over r, LDS atomic accumulate ----
    #pragma unroll 1
    for (int j = 0; j < 9; ++j) {
        const int cb = chh * 144 + j * 16 + q * 4;
        const float4 b4 = *(const float4*)(bi + cb);
        float a1[4] = {0.f, 0.f, 0.f, 0.f}, a2[4] = {0.f, 0.f, 0.f, 0.f};
        #pragma unroll
        for (int t = 0; t < 2; ++t) {
            float v0 = fmaxf(acc[t][j][0] + b4.x, 0.0f);
            float v1 = fmaxf(acc[t][j][1] + b4.y, 0.0f);
            float v2 = fmaxf(acc[t][j][2] + b4.z, 0.0f);
            float v3 = fmaxf(acc[t][j][3] + b4.w, 0.0f);
            a1[0] += v0; a1[1] += v1; a1[2] += v2; a1[3] += v3;
            a2[0] += v0 * v0; a2[1] += v1 * v1; a2[2] += v2 * v2; a2[3] += v3 * v3;
        }
        #pragma unroll
        for (int m = 1; m < 16; m <<= 1) {
            #pragma unroll
            for (int i = 0; i < 4; ++i) {
                a1[i] += __shfl_xor(a1[i], m, 64);
                a2[i] += __shfl_xor(a2[i], m, 64);
            }
        }
        if (r == 0) {
            #pragma unroll
            for (int i = 0; i < 4; ++i) {
                atomicAdd(&sstat[cb + i], a1[i]);
                atomicAdd(&sstat[288 + cb + i], a2[i]);
            }
        }
    }

    // ---- two-phase coalesced store of the 64x288 bf16 tile ----
    #pragma unroll
    for (int ph = 0; ph < 2; ++ph) {
        // stage: this wave's 16-px x 144-c piece for phase ph
        const int lr = pxh * 16 + r;     // local row 0..31
        #pragma unroll
        for (int j = 0; j < 9; ++j) {
            const int cb = chh * 144 + j * 16 + q * 4;
            const float4 b4 = *(const float4*)(bi + cb);
            unsigned short h[4];
            h[0] = f2b(fmaxf(acc[ph][j][0] + b4.x, 0.0f));
            h[1] = f2b(fmaxf(acc[ph][j][1] + b4.y, 0.0f));
            h[2] = f2b(fmaxf(acc[ph][j][2] + b4.z, 0.0f));
            h[3] = f2b(fmaxf(acc[ph][j][3] + b4.w, 0.0f));
            *(uint2*)(smc + lr * 576 + cb * 2) = *(const uint2*)h;
        }
        __syncthreads();
        // cooperative contiguous store: 32 rows x 36 chunks of 16 B
        for (int idx = tid; idx < 1152; idx += 256) {
            const int row = idx / 36;
            const int off = idx - row * 36;
            const int gpx = p0 + ph * 16 + row + (row & 16);
            *(uint4*)(xt + (size_t)gpx * CH + off * 8) =
                *(const uint4*)(smc + row * 576 + off * 16);
        }
        if (ph == 0) {
            // flush stats (s2g is contiguous after s1g in ws)
            for (int c2 = tid; c2 < 576; c2 += 256)
                atomicAdd(&s1g[c2], sstat[c2]);
        }
        __syncthreads();
    }
}

// ---------------------------------------------------------------------------
// K2a: BN scale/shift
// ---------------------------------------------------------------------------
__global__ __launch_bounds__(320) void k_scale(const float* __restrict__ s1,
                                               const float* __restrict__ s2,
                                               const float* __restrict__ gamma,
                                               const float* __restrict__ beta,
                                               float* __restrict__ scale,
                                               float* __restrict__ shift) {
    const int c = threadIdx.x;
    if (c < CH) {
        const float inv = 1.0f / (float)(NB * HW);
        const float mean = s1[c] * inv;
        const float var  = s2[c] * inv - mean * mean;
        const float rs   = rsqrtf(var + BN_EPS);
        const float sc   = gamma[c] * rs;
        scale[c] = sc;
        shift[c] = beta[c] - mean * sc;
    }
}

// ---------------------------------------------------------------------------
// K2b: Wo_s[m][k] = bf16(Wo[m][k]*scale[k]); bo2[m] = bo[m] + Wo[m][:]@shift
// ---------------------------------------------------------------------------
__global__ __launch_bounds__(64) void k_fold(const float* __restrict__ Wo,
                                             const float* __restrict__ bo,
                                             const float* __restrict__ scale,
                                             const float* __restrict__ shift,
                                             unsigned short* __restrict__ Wos,
                                             float* __restrict__ bo2) {
    const int m = blockIdx.x;
    const int t = threadIdx.x;
    float s = 0.0f;
    for (int k = t; k < CH; k += 64) {
        const float wv = Wo[(size_t)m * CH + k];
        s += wv * shift[k];
        Wos[(size_t)m * CH + k] = f2b(wv * scale[k]);
    }
    #pragma unroll
    for (int off = 32; off > 0; off >>= 1) s += __shfl_down(s, off, 64);
    if (t == 0) bo2[m] = bo[m] + s;
}

// ---------------------------------------------------------------------------
// K3: LDS-staged MFMA GEMM2 (ker = Wo_s @ tmp + bo2) -> kerL -> involution.
// Block: 32 px x 288 ker-ch, 4 waves; wave = 16 px x 144 c (9 tiles).
// ---------------------------------------------------------------------------
#define KLS 36
__global__ __launch_bounds__(256) void k_gemm2_invol(const unsigned short* __restrict__ xt,
                                                     const unsigned short* __restrict__ Wos,
                                                     const float* __restrict__ bo2,
                                                     const float* __restrict__ x,
                                                     float* __restrict__ out) {
    __shared__ unsigned short smem[CH * KLS];   // 20736 B
    char* smc = (char*)smem;
    unsigned short* kerL = smem;

    const int tid  = threadIdx.x;
    const int wave = tid >> 6;
    const int lane = tid & 63;
    const int q    = lane >> 4;
    const int r    = lane & 15;
    const int pxh  = wave & 1;
    const int chh  = wave >> 1;
    const int p0   = blockIdx.x * 32;
    const int b    = blockIdx.y;
    const int h    = p0 >> 6;
    const int w0   = p0 & 63;
    const size_t rowbase = (size_t)b * HW + p0;

    f32x4 acc[9];
    #pragma unroll
    for (int j = 0; j < 9; ++j) acc[j] = (f32x4)0.0f;

    const int lrow = lane >> 2;
    const int lp   = lane & 3;

    for (int k0 = 0; k0 < CH; k0 += 32) {
        for (int s = wave; s < 20; s += 4) {
            const int row = s * 16 + lrow;            // 0..319
            const int sc  = lp ^ ((row >> 1) & 3);
            const unsigned short* g = (s < 18)
                ? Wos + (size_t)row * CH + k0 + sc * 8
                : xt  + (rowbase + row - 288) * CH + k0 + sc * 8;
            GLDS(g, smc + s * 1024);
        }
        __syncthreads();
        const int xr = 288 + pxh * 16 + r;
        const bf16x8 xf = *(const bf16x8*)(smc + xr * 64 + ((q ^ ((xr >> 1) & 3)) * 16));
        #pragma unroll
        for (int j = 0; j < 9; ++j) {
            const int wr = chh * 144 + j * 16 + r;
            const bf16x8 wf = *(const bf16x8*)(smc + wr * 64 + ((q ^ ((wr >> 1) & 3)) * 16));
            acc[j] = mfma16(wf, xf, acc[j]);
        }
        __syncthreads();
    }

    const int pxl = pxh * 16 + r;
    #pragma unroll
    for (int j = 0; j < 9; ++j) {
        const int cb = chh * 144 + j * 16 + q * 4;
        const float4 bz = *(const float4*)(bo2 + cb);
        kerL[(cb + 0) * KLS + pxl] = f2b(acc[j][0] + bz.x);
        kerL[(cb + 1) * KLS + pxl] = f2b(acc[j][1] + bz.y);
        kerL[(cb + 2) * KLS + pxl] = f2b(acc[j][2] + bz.z);
        kerL[(cb + 3) * KLS + pxl] = f2b(acc[j][3] + bz.w);
    }
    __syncthreads();

    const int tm = tid >> 3;
    const int tn = tid & 7;
    const int wb = w0 + tn * 4;
    #pragma unroll 1
    for (int i = 0; i < 9; ++i) {
        const int ch = tm + 32 * i;
        const int cb = (ch / CPG) * CPG;
        float xv[3][6];
        #pragma unroll
        for (int dr = 0; dr < 3; ++dr) {
            const int hh = h + dr - 1;
            const bool rv = (hh >= 0) && (hh < IMH);
            const float* xr2 = x + ((size_t)(b * CH + ch) * IMH + (rv ? hh : 0)) * IMW;
            if (rv) {
                const float4 m4 = *(const float4*)(xr2 + wb);
                xv[dr][1] = m4.x; xv[dr][2] = m4.y; xv[dr][3] = m4.z; xv[dr][4] = m4.w;
                xv[dr][0] = (wb > 0)       ? xr2[wb - 1] : 0.0f;
                xv[dr][5] = (wb + 4 < IMW) ? xr2[wb + 4] : 0.0f;
            } else {
                #pragma unroll
                for (int j = 0; j < 6; ++j) xv[dr][j] = 0.0f;
            }
        }
        float o[4] = {0.0f, 0.0f, 0.0f, 0.0f};
        #pragma unroll
        for (int k = 0; k < 9; ++k) {
            const int dr = k / 3, dc = k % 3;
            const uint2 kk = *(const uint2*)(kerL + (cb + k) * KLS + tn * 4);
            const unsigned short* ks = (const unsigned short*)&kk;
            #pragma unroll
            for (int j = 0; j < 4; ++j)
                o[j] += b2f(ks[j]) * xv[dr][j + dc];
        }
        float4 ov = {o[0], o[1], o[2], o[3]};
        *(float4*)(out + ((size_t)(b * CH + ch) * IMH + h) * IMW + wb) = ov;
    }
}

// ---------------------------------------------------------------------------
extern "C" void kernel_launch(void* const* d_in, const int* in_sizes, int n_in,
                              void* d_out, int out_size, void* d_ws, size_t ws_size,
                              hipStream_t stream) {
    const float* x     = (const float*)d_in[0];
    const float* Wi    = (const float*)d_in[1];
    const float* bi    = (const float*)d_in[2];
    const float* gamma = (const float*)d_in[3];
    const float* beta  = (const float*)d_in[4];
    const float* Wo    = (const float*)d_in[5];
    const float* bo    = (const float*)d_in[6];
    float* out = (float*)d_out;

    char* ws = (char*)d_ws;
    unsigned short* xt  = (unsigned short*)(ws + XT_OFF);
    unsigned short* Wib = (unsigned short*)(ws + WIB_OFF);
    unsigned short* Wos = (unsigned short*)(ws + WOS_OFF);
    float* s1    = (float*)(ws + S1_OFF);
    float* s2    = (float*)(ws + S2_OFF);
    float* scale = (float*)(ws + SC_OFF);
    float* shift = (float*)(ws + SH_OFF);
    float* bo2   = (float*)(ws + BO2_OFF);

    k_transpose<<<dim3(HW / 64, CH / 32, NB), 256, 0, stream>>>(x, xt);
    k_cvt_wi<<<dim3(CH * CH / 1024), 256, 0, stream>>>(Wi, Wib);
    hipMemsetAsync(ws + S1_OFF, 0, 2 * CH * sizeof(float), stream);
    k_gemm1<<<dim3(NPX / 64), 256, 0, stream>>>(Wib, bi, xt, s1);
    k_scale<<<dim3(1), 320, 0, stream>>>(s1, s2, gamma, beta, scale, shift);
    k_fold<<<dim3(CH), 64, 0, stream>>>(Wo, bo, scale, shift, Wos, bo2);
    k_gemm2_invol<<<dim3(HW / 32, NB), 256, 0, stream>>>(xt, Wos, bo2, x, out);
}